// Round 8
// baseline (348.866 us; speedup 1.0000x reference)
//
#include <hip/hip_runtime.h>
#include <stdint.h>

typedef unsigned short u16;
typedef unsigned int u32;
typedef __attribute__((ext_vector_type(8))) short bf16x8;
typedef __attribute__((ext_vector_type(4))) float f32x4;
typedef __attribute__((ext_vector_type(4))) u32 u32x4;

#define DS 2048
#define NROWS 16384
#define MS 1024
#define K2 2048

__device__ __forceinline__ u16 f2bf(float f) {
  u32 u = __float_as_uint(f);
  u32 r = (u + 0x7fffu + ((u >> 16) & 1u)) >> 16;
  return (u16)r;
}

// ---------------- merged f32->bf16 convert: W -> Wbf, S -> Sbf + Bt even rows --
#define NW4 (DS * DS / 4)
#define NS4 (MS * DS / 4)
__global__ __launch_bounds__(256) void k_conv_WS(const float* __restrict__ W,
                                                 const float* __restrict__ S,
                                                 u16* __restrict__ Wbf,
                                                 u16* __restrict__ Sbf,
                                                 u16* __restrict__ Bt) {
  int i = blockIdx.x * 256 + threadIdx.x;
  if (i < NW4) {
    float4 v = ((const float4*)W)[i];
    ushort4 o;
    o.x = f2bf(v.x); o.y = f2bf(v.y); o.z = f2bf(v.z); o.w = f2bf(v.w);
    ((ushort4*)Wbf)[i] = o;
  } else {
    int j = i - NW4;
    float4 v = ((const float4*)S)[j];
    ushort4 o;
    o.x = f2bf(v.x); o.y = f2bf(v.y); o.z = f2bf(v.z); o.w = f2bf(v.w);
    ((ushort4*)Sbf)[j] = o;
    int m = j >> 9;
    int c4 = j & 511;
    ((ushort4*)Bt)[(size_t)m * 1024 + c4] = o;  // interleaved row 2m = S[m]
  }
}

// ---------------- async global->LDS, 16B per lane ----------------
__device__ __forceinline__ void gload16(const u16* g, u16* l) {
  __builtin_amdgcn_global_load_lds(
      (const __attribute__((address_space(1))) void*)g,
      (__attribute__((address_space(3))) void*)l, 16, 0, 0);
}

#define VMW3() asm volatile("s_waitcnt vmcnt(3)" ::: "memory")
#define VMW0f() asm volatile("s_waitcnt vmcnt(0)" ::: "memory")
#define RBAR() __builtin_amdgcn_s_barrier()
#define RSB0() __builtin_amdgcn_sched_barrier(0)

// ------ 64x128 bt-GEMM for V = S @ W^T (256 blocks), 2-deep LDS dbuf ---------
__global__ __launch_bounds__(256, 2) void k_gemm_bt64(const u16* __restrict__ A,
                                                      const u16* __restrict__ Bt,
                                                      u16* __restrict__ C, int ldc,
                                                      int K) {
  __shared__ u16 lsA[2][64 * 32];
  __shared__ u16 lsB[2][128 * 32];
  const int tid = threadIdx.x;
  const int wid = tid >> 6;
  const int lane = tid & 63;
  const int brow = blockIdx.y * 64;
  const int bcol = blockIdx.x * 128;
  const int wm = wid >> 1;
  const int wn = wid & 1;

  f32x4 acc[2][4];
#pragma unroll
  for (int i = 0; i < 2; ++i)
#pragma unroll
    for (int j = 0; j < 4; ++j) acc[i][j] = (f32x4){0.f, 0.f, 0.f, 0.f};

  const int srow = lane >> 2;
  const int skoct = (lane & 3) * 8;
  const u16* gA = A + (size_t)(brow + wid * 16 + srow) * K + skoct;
  const u16* gB = Bt + (size_t)(bcol + wid * 32 + srow) * K + skoct;
  const size_t row16 = (size_t)16 * K;

  const int arow = wm * 32 + (lane & 15);
  const int bcr = wn * 64 + (lane & 15);
  const int koff = (lane >> 4) * 8;

#define VSTG(b, kt)                                        \
  do {                                                     \
    gload16(gA + (kt), &lsA[b][(wid * 16) * 32]);          \
    gload16(gB + (kt), &lsB[b][(wid * 32) * 32]);          \
    gload16(gB + (kt) + row16, &lsB[b][(wid * 32 + 16) * 32]); \
  } while (0)

  VSTG(0, 0);
  const int NT = K / 32;  // 64
#pragma unroll 1
  for (int t = 0; t < NT; ++t) {
    const int b = t & 1;
    if (t < NT - 1) {
      VSTG(b ^ 1, (t + 1) * 32);
      VMW3();
    } else {
      VMW0f();
    }
    RBAR(); RSB0();
    bf16x8 af[2], bfr[4];
#pragma unroll
    for (int i = 0; i < 2; ++i)
      af[i] = *(const bf16x8*)&lsA[b][(arow + i * 16) * 32 + koff];
#pragma unroll
    for (int i = 0; i < 4; ++i)
      bfr[i] = *(const bf16x8*)&lsB[b][(bcr + i * 16) * 32 + koff];
#pragma unroll
    for (int mi = 0; mi < 2; ++mi)
#pragma unroll
      for (int ni = 0; ni < 4; ++ni)
        acc[mi][ni] = __builtin_amdgcn_mfma_f32_16x16x32_bf16(af[mi], bfr[ni],
                                                              acc[mi][ni], 0, 0, 0);
    RSB0();
    RBAR();
  }
#undef VSTG

  const int crow0 = brow + wm * 32 + (lane >> 4) * 4;
  const int ccol0 = bcol + wn * 64 + (lane & 15);
#pragma unroll
  for (int mi = 0; mi < 2; ++mi)
#pragma unroll
    for (int ni = 0; ni < 4; ++ni)
#pragma unroll
      for (int r = 0; r < 4; ++r)
        C[(size_t)(crow0 + mi * 16 + r) * ldc + (ccol0 + ni * 16)] = f2bf(acc[mi][ni][r]);
}

// ========== 256^2 8-phase GEMM (r4 schedule) + fused D-convert + epilogue =====
// r8: r6 kernel verbatim (absmax-0-verified) with __launch_bounds__(512,1):
// LDS (128KB) already limits to 1 block/CU, so the 128-VGPR cap was pure loss —
// the 256-VGPR cap fits the reg-staged A path (f32 load -> cvt_pk -> ds_write)
// without scratch spills.
#define SINV 0.022097086912079608f

#define DSR(d, a, IMM) \
  asm volatile("ds_read_b128 %0, %1 offset:%c2" : "=v"(d) : "v"(a), "n"(IMM))
#define GLD4o(d, a, IMM) \
  asm volatile("global_load_dwordx4 %0, %1, off offset:%c2" : "=v"(d) : "v"(a), "n"(IMM))
#define CVTPK(d, lo, hi) \
  asm("v_cvt_pk_bf16_f32 %0, %1, %2" : "=v"(d) : "v"(lo), "v"(hi))

#define RD_A0(k0, k1, dst)                              \
  DSR(dst[0][0], k0, 0);     DSR(dst[0][1], k1, 0);     \
  DSR(dst[1][0], k0, 2048);  DSR(dst[1][1], k1, 2048);  \
  DSR(dst[2][0], k0, 4096);  DSR(dst[2][1], k1, 4096);  \
  DSR(dst[3][0], k0, 6144);  DSR(dst[3][1], k1, 6144)
#define RD_A1(k0, k1, dst)                              \
  DSR(dst[0][0], k0, 16384); DSR(dst[0][1], k1, 16384); \
  DSR(dst[1][0], k0, 18432); DSR(dst[1][1], k1, 18432); \
  DSR(dst[2][0], k0, 20480); DSR(dst[2][1], k1, 20480); \
  DSR(dst[3][0], k0, 22528); DSR(dst[3][1], k1, 22528)
#define RD_B0(k0, k1, dst)                              \
  DSR(dst[0][0], k0, 0);     DSR(dst[0][1], k1, 0);     \
  DSR(dst[1][0], k0, 2048);  DSR(dst[1][1], k1, 2048)
#define RD_B1(k0, k1, dst)                              \
  DSR(dst[0][0], k0, 16384); DSR(dst[0][1], k1, 16384); \
  DSR(dst[1][0], k0, 18432); DSR(dst[1][1], k1, 18432)

#define MMAQ(AF, BQ, QM, QN)                                                       \
  do {                                                                             \
    _Pragma("unroll") for (int mi = 0; mi < 4; ++mi)                               \
        _Pragma("unroll") for (int ni = 0; ni < 2; ++ni) {                         \
      acc[QM][QN][mi][ni] = __builtin_amdgcn_mfma_f32_16x16x32_bf16(               \
          AF[mi][0], BQ[ni][0], acc[QM][QN][mi][ni], 0, 0, 0);                     \
      acc[QM][QN][mi][ni] = __builtin_amdgcn_mfma_f32_16x16x32_bf16(               \
          AF[mi][1], BQ[ni][1], acc[QM][QN][mi][ni], 0, 0, 0);                     \
    }                                                                              \
  } while (0)

#define LGKM(N)                                              \
  asm volatile("s_waitcnt lgkmcnt(" #N ")" ::: "memory");    \
  __builtin_amdgcn_sched_barrier(0)
#define VMW(N) asm volatile("s_waitcnt vmcnt(" #N ")" ::: "memory")
#define SB0() __builtin_amdgcn_sched_barrier(0)
#define PRIO1() __builtin_amdgcn_s_setprio(1)
#define PRIO0() __builtin_amdgcn_s_setprio(0)
#define BAR() __builtin_amdgcn_s_barrier()

#define STGB(b, h, kt)                                                            \
  do {                                                                            \
    gload16(pB + (size_t)((h) * 128) * K2 + (kt),                                 \
            &lds[(b) * 32768 + 16384 + (h) * 8192 + wid * 512]);                  \
    gload16(pB + (size_t)((h) * 128 + 64) * K2 + (kt),                            \
            &lds[(b) * 32768 + 16384 + (h) * 8192 + 4096 + wid * 512]);           \
  } while (0)

#define ALOAD(R, h, kt)                                                           \
  do {                                                                            \
    const float* _p0 = pAf + (size_t)((h) * 128) * 2048 + (kt);                   \
    const float* _p1 = _p0 + (size_t)64 * 2048;                                   \
    GLD4o(R[0], _p0, 0); GLD4o(R[1], _p0, 16);                                    \
    GLD4o(R[2], _p1, 0); GLD4o(R[3], _p1, 16);                                    \
  } while (0)
#define AWRITE(R, b, h)                                                           \
  do {                                                                            \
    u32 c0, c1, c2, c3, c4, c5, c6, c7;                                           \
    CVTPK(c0, R[0][0], R[0][1]); CVTPK(c1, R[0][2], R[0][3]);                     \
    CVTPK(c2, R[1][0], R[1][1]); CVTPK(c3, R[1][2], R[1][3]);                     \
    CVTPK(c4, R[2][0], R[2][1]); CVTPK(c5, R[2][2], R[2][3]);                     \
    CVTPK(c6, R[3][0], R[3][1]); CVTPK(c7, R[3][2], R[3][3]);                     \
    u32x4 Q0 = {c0, c1, c2, c3}, Q1 = {c4, c5, c6, c7};                           \
    u32 wa = wbase + (b)*65536u + (h)*16384u;                                     \
    asm volatile("ds_write_b128 %0, %1" ::"v"(wa), "v"(Q0));                      \
    asm volatile("ds_write_b128 %0, %1 offset:8192" ::"v"(wa), "v"(Q1));          \
  } while (0)

__global__ __launch_bounds__(512, 1) void k_gemm8(const float* __restrict__ Af,
                                                  const u16* __restrict__ Bt,
                                                  float* __restrict__ Pnd) {
  extern __shared__ u16 lds[];
  const int tid = threadIdx.x;
  const int wid = tid >> 6;
  const int lane = tid & 63;
  const int bid = blockIdx.x;
  const int swz = (bid & 7) * 64 + (bid >> 3);
  const int by = swz >> 3, bx = swz & 7;
  const int brow = by * 256, bcol = bx * 256;
  const int wm = wid >> 2, wn = wid & 3;
  const int l15 = lane & 15, s0 = lane >> 4;

  const int tr = tid >> 3;
  const int scol = ((tid & 7) ^ (tr & 7)) << 3;
  const float* pAf = Af + (size_t)(brow + tr) * 2048 + scol;
  const u16* pB = Bt + (size_t)(bcol + tr) * K2 + scol;

  const u32 lb = (u32)(uintptr_t)(&lds[0]);
  const u32 wbase = lb + (u32)wid * 1024u + (u32)(lane * 16);
  const u32 xorp = ((u32)(s0 ^ (lane & 7))) << 4;
  const u32 aA00 = lb + ((u32)(wm * 64 + l15) << 7) + xorp;
  const u32 aA01 = aA00 ^ 64u;
  const u32 aA10 = aA00 + 65536u;
  const u32 aA11 = aA10 ^ 64u;
  const u32 aB00 = lb + 32768u + ((u32)(wn * 32 + l15) << 7) + xorp;
  const u32 aB01 = aB00 ^ 64u;
  const u32 aB10 = aB00 + 65536u;
  const u32 aB11 = aB10 ^ 64u;

  f32x4 acc[2][2][4][2];
#pragma unroll
  for (int a = 0; a < 2; ++a)
#pragma unroll
    for (int b = 0; b < 2; ++b)
#pragma unroll
      for (int c = 0; c < 4; ++c)
#pragma unroll
        for (int d = 0; d < 2; ++d) acc[a][b][c][d] = (f32x4){0.f, 0.f, 0.f, 0.f};

  bf16x8 afA[4][2], afB[4][2], bq0[2][2], bq1[2][2];
  f32x4 ra0[4], ra1[4];

  // ---- prologue: B buf0 via gload; A buf0 h0,h1 + buf1 h0 via reg path ----
  STGB(0, 0, 0); STGB(0, 1, 0);
  ALOAD(ra0, 0, 0);  VMW(0); SB0(); AWRITE(ra0, 0, 0);
  ALOAD(ra0, 1, 0);  VMW(0); SB0(); AWRITE(ra0, 0, 1);
  ALOAD(ra0, 0, 64); VMW(0); SB0(); AWRITE(ra0, 1, 0);
  LGKM(0);
  BAR();
  RD_A0(aA00, aA01, afA);
  RD_B0(aB00, aB01, bq0);

  int kb = 0;
#pragma unroll 1
  for (int j = 0; j < 15; ++j, kb += 128) {
    // P1
    STGB(1, 0, kb + 64);
    ALOAD(ra0, 1, kb + 64);
    RD_B1(aB00, aB01, bq1);
    LGKM(4); PRIO1(); MMAQ(afA, bq0, 0, 0); PRIO0(); BAR();
    // P2
    STGB(1, 1, kb + 64);
    ALOAD(ra1, 0, kb + 128);
    RD_A1(aA00, aA01, afB);
    LGKM(8); PRIO1(); MMAQ(afA, bq1, 0, 1); PRIO0(); BAR();
    // P3
    LGKM(0); PRIO1(); MMAQ(afB, bq0, 1, 0); PRIO0();
    VMW(6); SB0(); AWRITE(ra0, 1, 1); BAR();
    // P4
    VMW(0); SB0();
    RD_A0(aA10, aA11, afA);
    RD_B0(aB10, aB11, bq0);
    LGKM(12); PRIO1(); MMAQ(afB, bq1, 1, 1); PRIO0();
    AWRITE(ra1, 0, 0); BAR();
    // P5
    STGB(0, 0, kb + 128);
    ALOAD(ra0, 1, kb + 128);
    RD_B1(aB10, aB11, bq1);
    LGKM(4); PRIO1(); MMAQ(afA, bq0, 0, 0); PRIO0(); BAR();
    // P6
    STGB(0, 1, kb + 128);
    ALOAD(ra1, 0, kb + 192);
    RD_A1(aA10, aA11, afB);
    LGKM(8); PRIO1(); MMAQ(afA, bq1, 0, 1); PRIO0(); BAR();
    // P7
    LGKM(0); PRIO1(); MMAQ(afB, bq0, 1, 0); PRIO0();
    VMW(6); SB0(); AWRITE(ra0, 0, 1); BAR();
    // P8
    VMW(0); SB0();
    RD_A0(aA00, aA01, afA);
    RD_B0(aB00, aB01, bq0);
    LGKM(12); PRIO1(); MMAQ(afB, bq1, 1, 1); PRIO0();
    AWRITE(ra1, 1, 0); BAR();
  }
  // ---- tail: tiles 30 (buf0) + 31 (buf1); kb == 1920 ----
  {
    STGB(1, 0, kb + 64);
    ALOAD(ra0, 1, kb + 64);
    RD_B1(aB00, aB01, bq1);
    LGKM(4); PRIO1(); MMAQ(afA, bq0, 0, 0); PRIO0(); BAR();
    STGB(1, 1, kb + 64);
    RD_A1(aA00, aA01, afB);
    LGKM(8); PRIO1(); MMAQ(afA, bq1, 0, 1); PRIO0(); BAR();
    LGKM(0); PRIO1(); MMAQ(afB, bq0, 1, 0); PRIO0();
    VMW(2); SB0(); AWRITE(ra0, 1, 1); BAR();
    VMW(0); SB0();
    RD_A0(aA10, aA11, afA);
    RD_B0(aB10, aB11, bq0);
    LGKM(12); PRIO1(); MMAQ(afB, bq1, 1, 1); PRIO0(); BAR();
    RD_B1(aB10, aB11, bq1);
    LGKM(4); PRIO1(); MMAQ(afA, bq0, 0, 0); PRIO0();
    RD_A1(aA10, aA11, afB);
    LGKM(8); PRIO1(); MMAQ(afA, bq1, 0, 1); PRIO0();
    LGKM(0); PRIO1(); MMAQ(afB, bq0, 1, 0); MMAQ(afB, bq1, 1, 1); PRIO0();
  }

  // ---------------- fused epilogue ----------------
  __syncthreads();
  float* red = (float*)&lds[0];

#pragma unroll
  for (int qm = 0; qm < 2; ++qm)
#pragma unroll
    for (int mi = 0; mi < 4; ++mi)
#pragma unroll
      for (int r = 0; r < 4; ++r) {
        float num = 0.f, den = 0.f;
#pragma unroll
        for (int qn = 0; qn < 2; ++qn)
#pragma unroll
          for (int ni = 0; ni < 2; ++ni) {
            float v = acc[qm][qn][mi][ni][r];
            float g = __shfl_xor(v, 1);
            float e = __expf(v * SINV);
            num += e * g;
            den += e;
          }
        num += __shfl_xor(num, 2); den += __shfl_xor(den, 2);
        num += __shfl_xor(num, 4); den += __shfl_xor(den, 4);
        num += __shfl_xor(num, 8); den += __shfl_xor(den, 8);
        if (l15 == 0) {
          int slot = qm * 16 + mi * 4 + r;
          red[((wid * 32 + slot) * 4 + s0) * 2 + 0] = num;
          red[((wid * 32 + slot) * 4 + s0) * 2 + 1] = den;
        }
      }
  __syncthreads();
  {
    int rloc = tid >> 1, which = tid & 1;
    int qm = rloc >> 7, wmr = (rloc >> 6) & 1, mi = (rloc >> 4) & 3;
    int lg = (rloc >> 2) & 3, r = rloc & 3;
    int slot = qm * 16 + mi * 4 + r;
    float v = 0.f;
#pragma unroll
    for (int w2 = 0; w2 < 4; ++w2)
      v += red[(((wmr * 4 + w2) * 32 + slot) * 4 + lg) * 2 + which];
    Pnd[((size_t)(brow + rloc) * 8 + bx) * 2 + which] = v;
  }
}

// ---------------- per-row finish ----------------
__global__ __launch_bounds__(256) void k_rowfinal(const float* __restrict__ Pnd,
                                                  float* __restrict__ part) {
  int row = blockIdx.x * 256 + threadIdx.x;
  const float4* p = (const float4*)(Pnd + (size_t)row * 16);
  float num = 0.f, den = 0.f;
#pragma unroll
  for (int i = 0; i < 4; ++i) {
    float4 v = p[i];
    num += v.x + v.z;
    den += v.y + v.w;
  }
  float logit = num / den;
  float ls = (logit >= 0.f) ? -log1pf(__expf(-logit))
                            : (logit - log1pf(__expf(logit)));
  __shared__ float red[4];
#pragma unroll
  for (int off = 32; off > 0; off >>= 1) ls += __shfl_down(ls, off);
  if ((threadIdx.x & 63) == 0) red[threadIdx.x >> 6] = ls;
  __syncthreads();
  if (threadIdx.x == 0) part[blockIdx.x] = red[0] + red[1] + red[2] + red[3];
}

__global__ __launch_bounds__(64) void k_final64(const float* __restrict__ part,
                                                float* __restrict__ out) {
  float v = part[threadIdx.x];
#pragma unroll
  for (int off = 32; off > 0; off >>= 1) v += __shfl_down(v, off);
  if (threadIdx.x == 0) out[0] = v;
}

extern "C" void kernel_launch(void* const* d_in, const int* in_sizes, int n_in,
                              void* d_out, int out_size, void* d_ws, size_t ws_size,
                              hipStream_t stream) {
  const float* D = (const float*)d_in[0];
  const float* S = (const float*)d_in[1];
  const float* W = (const float*)d_in[2];

  char* w = (char*)d_ws;
  u16* Bt = (u16*)w;  w += (size_t)DS * DS * 2;          // 8 MB (interleaved S/V)
  u16* Wbf = (u16*)w; w += (size_t)DS * DS * 2;          // 8 MB
  u16* Sbf = (u16*)w; w += (size_t)MS * DS * 2;          // 4 MB
  float* Pnd = (float*)w; w += (size_t)NROWS * 16 * 4;   // 1 MB
  float* part = (float*)w;                               // 256 B

  (void)hipFuncSetAttribute((const void*)k_gemm8,
                            hipFuncAttributeMaxDynamicSharedMemorySize, 131072);

  k_conv_WS<<<(NW4 + NS4) / 256, 256, 0, stream>>>(W, S, Wbf, Sbf, Bt);

  // V = S @ W^T into Bt odd rows (ldc = 4096, base = Bt + 2048)
  k_gemm_bt64<<<dim3(DS / 128, MS / 64), 256, 0, stream>>>(
      Sbf, Wbf, Bt + DS, 2 * DS, DS);

  // fused: D f32 read + convert + GEMM + softmax-pair epilogue
  k_gemm8<<<512, 512, 131072, stream>>>(D, Bt, Pnd);

  k_rowfinal<<<NROWS / 256, 256, 0, stream>>>(Pnd, part);
  k_final64<<<1, 64, 0, stream>>>(part, (float*)d_out);
}

// Round 9
// 169.764 us; speedup vs baseline: 2.0550x; 2.0550x over previous
//
#include <hip/hip_runtime.h>
#include <stdint.h>

typedef unsigned short u16;
typedef unsigned int u32;
typedef __attribute__((ext_vector_type(8))) short bf16x8;
typedef __attribute__((ext_vector_type(4))) float f32x4;
typedef __attribute__((ext_vector_type(4))) u32 u32x4;

#define DS 2048
#define NROWS 16384
#define MS 1024
#define K2 2048

__device__ __forceinline__ u16 f2bf(float f) {
  u32 u = __float_as_uint(f);
  u32 r = (u + 0x7fffu + ((u >> 16) & 1u)) >> 16;
  return (u16)r;
}

// ---------------- async global->LDS, 16B per lane ----------------
__device__ __forceinline__ void gload16(const u16* g, u16* l) {
  __builtin_amdgcn_global_load_lds(
      (const __attribute__((address_space(1))) void*)g,
      (__attribute__((address_space(3))) void*)l, 16, 0, 0);
}

#define DSR(d, a, IMM) \
  asm volatile("ds_read_b128 %0, %1 offset:%c2" : "=v"(d) : "v"(a), "n"(IMM))
#define CVTPK(d, lo, hi) \
  asm("v_cvt_pk_bf16_f32 %0, %1, %2" : "=v"(d) : "v"(lo), "v"(hi))
#define LGKM(N)                                              \
  asm volatile("s_waitcnt lgkmcnt(" #N ")" ::: "memory");    \
  __builtin_amdgcn_sched_barrier(0)
#define VMW(N) asm volatile("s_waitcnt vmcnt(" #N ")" ::: "memory")
#define SB0() __builtin_amdgcn_sched_barrier(0)
#define PRIO1() __builtin_amdgcn_s_setprio(1)
#define PRIO0() __builtin_amdgcn_s_setprio(0)
#define BAR() __builtin_amdgcn_s_barrier()

// cvt 2x f32x4 -> bf16x8 (element order k0..k7)
#define CVT8(dst, lo, hi)                                         \
  do {                                                            \
    u32 _c0, _c1, _c2, _c3;                                       \
    CVTPK(_c0, lo[0], lo[1]); CVTPK(_c1, lo[2], lo[3]);           \
    CVTPK(_c2, hi[0], hi[1]); CVTPK(_c3, hi[2], hi[3]);           \
    u32x4 _q = {_c0, _c1, _c2, _c3};                              \
    dst = *(bf16x8*)&_q;                                          \
  } while (0)

// ============ mega pre-kernel: V-GEMM(f32 in) + D convert + S->Bt ============
// blocks 0..255    : V = S @ W^T (f32 inputs, bf16 MFMA, write Bt odd rows)
// blocks 256..2303 : D f32 -> Dbf
// blocks 2304..2431: S f32 -> Bt even rows
__global__ __launch_bounds__(256) void k_pre(const float* __restrict__ D,
                                             const float* __restrict__ S,
                                             const float* __restrict__ W,
                                             u16* __restrict__ Dbf,
                                             u16* __restrict__ Bt) {
  __shared__ float lsA[2][64 * 32];
  __shared__ float lsB[2][128 * 32];
  const int bid = blockIdx.x;
  const int tid = threadIdx.x;

  if (bid >= 256) {
    if (bid < 2304) {  // D convert
      size_t i = (size_t)(bid - 256) * 256 + tid;
#pragma unroll
      for (int it = 0; it < 16; ++it, i += (size_t)2048 * 256) {
        float4 v = ((const float4*)D)[i];
        ushort4 o;
        o.x = f2bf(v.x); o.y = f2bf(v.y); o.z = f2bf(v.z); o.w = f2bf(v.w);
        ((ushort4*)Dbf)[i] = o;
      }
    } else {  // S -> Bt even rows (interleaved row 2m)
      size_t j = (size_t)(bid - 2304) * 256 + tid;
#pragma unroll
      for (int it = 0; it < 16; ++it, j += (size_t)128 * 256) {
        float4 v = ((const float4*)S)[j];
        ushort4 o;
        o.x = f2bf(v.x); o.y = f2bf(v.y); o.z = f2bf(v.z); o.w = f2bf(v.w);
        int m = (int)(j >> 9), c4 = (int)(j & 511);
        ((ushort4*)Bt)[(size_t)m * 1024 + c4] = o;
      }
    }
    return;
  }

  // ---- V-GEMM: 64x128 tile, K=2048, f32 staged to LDS, cvt at fragment ----
  const int wid = tid >> 6, lane = tid & 63;
  const int brow = (bid >> 4) * 64;   // m block
  const int bcol = (bid & 15) * 128;  // d block
  const int wm = wid >> 1, wn = wid & 1;
  const int l15 = lane & 15, s0 = lane >> 4;

  // staging source: pre-swizzled f32 octet (4 floats = 16B)
  const int sr = tid >> 3;
  const int soct = (tid & 7) ^ (sr & 7);
  const float* gS = S + (size_t)(brow + sr) * 2048 + soct * 4;
  const float* gW = W + (size_t)(bcol + sr) * 2048 + soct * 4;

  // ds_read bases: row*128B + ((2*s0)^ (l15&7))*16 ; pair addr = ^16
  const u32 lbA = (u32)(uintptr_t)&lsA[0][0];
  const u32 lbB = (u32)(uintptr_t)&lsB[0][0];
  const u32 swz = (u32)(((2 * s0) ^ (l15 & 7)) * 16);
  const u32 aA = lbA + (u32)(wm * 32 + l15) * 128 + swz;
  const u32 aAx = aA ^ 16u;
  const u32 aB = lbB + (u32)(wn * 64 + l15) * 128 + swz;
  const u32 aBx = aB ^ 16u;

  f32x4 acc[2][4];
#pragma unroll
  for (int i = 0; i < 2; ++i)
#pragma unroll
    for (int j = 0; j < 4; ++j) acc[i][j] = (f32x4){0.f, 0.f, 0.f, 0.f};

#define VSTG(b, kt)                                                              \
  do {                                                                           \
    gload16((const u16*)(gS + (kt)),             (u16*)(&lsA[b][0] + wid * 256)); \
    gload16((const u16*)(gS + 32 * 2048 + (kt)), (u16*)(&lsA[b][1024] + wid * 256)); \
    gload16((const u16*)(gW + (kt)),             (u16*)(&lsB[b][0] + wid * 256)); \
    gload16((const u16*)(gW + 32 * 2048 + (kt)), (u16*)(&lsB[b][1024] + wid * 256)); \
    gload16((const u16*)(gW + 64 * 2048 + (kt)), (u16*)(&lsB[b][2048] + wid * 256)); \
    gload16((const u16*)(gW + 96 * 2048 + (kt)), (u16*)(&lsB[b][3072] + wid * 256)); \
  } while (0)

  VSTG(0, 0);
#pragma unroll 1
  for (int t = 0; t < 64; ++t) {
    const int b = t & 1;
    const u32 oA = (u32)(b * 8192), oB = (u32)(b * 16384);
    if (t < 63) {
      VSTG(b ^ 1, (t + 1) * 32);
      VMW(6);
    } else {
      VMW(0);
    }
    BAR(); SB0();
    f32x4 qa0, qa1, qa2, qa3;
    f32x4 qb0, qb1, qb2, qb3, qb4, qb5, qb6, qb7;
    DSR(qa0, aA + oA, 0);     DSR(qa1, aAx + oA, 0);
    DSR(qa2, aA + oA, 2048);  DSR(qa3, aAx + oA, 2048);
    DSR(qb0, aB + oB, 0);     DSR(qb1, aBx + oB, 0);
    DSR(qb2, aB + oB, 2048);  DSR(qb3, aBx + oB, 2048);
    DSR(qb4, aB + oB, 4096);  DSR(qb5, aBx + oB, 4096);
    DSR(qb6, aB + oB, 6144);  DSR(qb7, aBx + oB, 6144);
    LGKM(0);
    bf16x8 af[2], bfr[4];
    CVT8(af[0], qa0, qa1); CVT8(af[1], qa2, qa3);
    CVT8(bfr[0], qb0, qb1); CVT8(bfr[1], qb2, qb3);
    CVT8(bfr[2], qb4, qb5); CVT8(bfr[3], qb6, qb7);
    PRIO1();
#pragma unroll
    for (int mi = 0; mi < 2; ++mi)
#pragma unroll
      for (int ni = 0; ni < 4; ++ni)
        acc[mi][ni] = __builtin_amdgcn_mfma_f32_16x16x32_bf16(af[mi], bfr[ni],
                                                              acc[mi][ni], 0, 0, 0);
    PRIO0(); SB0();
    BAR();  // all waves done reading buf b before next iter restages it
  }
#undef VSTG

  // write V -> Bt odd rows: Bt[(2*row+1)*2048 + col]
  const int crow0 = brow + wm * 32 + s0 * 4;
  const int ccol0 = bcol + wn * 64 + l15;
  u16* C = Bt + 2048;  // odd-row base, stride 4096
#pragma unroll
  for (int mi = 0; mi < 2; ++mi)
#pragma unroll
    for (int ni = 0; ni < 4; ++ni)
#pragma unroll
      for (int r = 0; r < 4; ++r)
        C[(size_t)(crow0 + mi * 16 + r) * 4096 + (ccol0 + ni * 16)] =
            f2bf(acc[mi][ni][r]);
}

// ================= 256^2 read-ahead 8-phase GEMM + fused softmax epilogue ======
// (exact r4/r7 kernel — verified 120.7 us, absmax 0)
#define SINV 0.022097086912079608f

#define RD_A0(k0, k1, dst)                              \
  DSR(dst[0][0], k0, 0);     DSR(dst[0][1], k1, 0);     \
  DSR(dst[1][0], k0, 2048);  DSR(dst[1][1], k1, 2048);  \
  DSR(dst[2][0], k0, 4096);  DSR(dst[2][1], k1, 4096);  \
  DSR(dst[3][0], k0, 6144);  DSR(dst[3][1], k1, 6144)
#define RD_A1(k0, k1, dst)                              \
  DSR(dst[0][0], k0, 16384); DSR(dst[0][1], k1, 16384); \
  DSR(dst[1][0], k0, 18432); DSR(dst[1][1], k1, 18432); \
  DSR(dst[2][0], k0, 20480); DSR(dst[2][1], k1, 20480); \
  DSR(dst[3][0], k0, 22528); DSR(dst[3][1], k1, 22528)
#define RD_B0(k0, k1, dst)                              \
  DSR(dst[0][0], k0, 0);     DSR(dst[0][1], k1, 0);     \
  DSR(dst[1][0], k0, 2048);  DSR(dst[1][1], k1, 2048)
#define RD_B1(k0, k1, dst)                              \
  DSR(dst[0][0], k0, 16384); DSR(dst[0][1], k1, 16384); \
  DSR(dst[1][0], k0, 18432); DSR(dst[1][1], k1, 18432)

#define MMAQ(AF, BQ, QM, QN)                                                       \
  do {                                                                             \
    _Pragma("unroll") for (int mi = 0; mi < 4; ++mi)                               \
        _Pragma("unroll") for (int ni = 0; ni < 2; ++ni) {                         \
      acc[QM][QN][mi][ni] = __builtin_amdgcn_mfma_f32_16x16x32_bf16(               \
          AF[mi][0], BQ[ni][0], acc[QM][QN][mi][ni], 0, 0, 0);                     \
      acc[QM][QN][mi][ni] = __builtin_amdgcn_mfma_f32_16x16x32_bf16(               \
          AF[mi][1], BQ[ni][1], acc[QM][QN][mi][ni], 0, 0, 0);                     \
    }                                                                              \
  } while (0)

#define STGA(b, h, kt)                                                            \
  do {                                                                            \
    gload16(pA + (size_t)((h) * 128) * K2 + (kt),                                 \
            &lds[(b) * 32768 + (h) * 8192 + wid * 512]);                          \
    gload16(pA + (size_t)((h) * 128 + 64) * K2 + (kt),                            \
            &lds[(b) * 32768 + (h) * 8192 + 4096 + wid * 512]);                   \
  } while (0)
#define STGB(b, h, kt)                                                            \
  do {                                                                            \
    gload16(pB + (size_t)((h) * 128) * K2 + (kt),                                 \
            &lds[(b) * 32768 + 16384 + (h) * 8192 + wid * 512]);                  \
    gload16(pB + (size_t)((h) * 128 + 64) * K2 + (kt),                            \
            &lds[(b) * 32768 + 16384 + (h) * 8192 + 4096 + wid * 512]);           \
  } while (0)

__global__ __launch_bounds__(512, 2) void k_gemm8(const u16* __restrict__ A,
                                                  const u16* __restrict__ Bt,
                                                  float* __restrict__ Pnd) {
  extern __shared__ u16 lds[];
  const int tid = threadIdx.x;
  const int wid = tid >> 6;
  const int lane = tid & 63;
  const int bid = blockIdx.x;
  const int swz = (bid & 7) * 64 + (bid >> 3);
  const int by = swz >> 3, bx = swz & 7;
  const int brow = by * 256, bcol = bx * 256;
  const int wm = wid >> 2, wn = wid & 3;
  const int l15 = lane & 15, s0 = lane >> 4;

  const int tr = tid >> 3;
  const int scol = ((tid & 7) ^ (tr & 7)) << 3;
  const u16* pA = A + (size_t)(brow + tr) * K2 + scol;
  const u16* pB = Bt + (size_t)(bcol + tr) * K2 + scol;

  const u32 lb = (u32)(uintptr_t)(&lds[0]);
  const u32 xorp = ((u32)(s0 ^ (lane & 7))) << 4;
  const u32 aA00 = lb + ((u32)(wm * 64 + l15) << 7) + xorp;
  const u32 aA01 = aA00 ^ 64u;
  const u32 aA10 = aA00 + 65536u;
  const u32 aA11 = aA10 ^ 64u;
  const u32 aB00 = lb + 32768u + ((u32)(wn * 32 + l15) << 7) + xorp;
  const u32 aB01 = aB00 ^ 64u;
  const u32 aB10 = aB00 + 65536u;
  const u32 aB11 = aB10 ^ 64u;

  f32x4 acc[2][2][4][2];
#pragma unroll
  for (int a = 0; a < 2; ++a)
#pragma unroll
    for (int b = 0; b < 2; ++b)
#pragma unroll
      for (int c = 0; c < 4; ++c)
#pragma unroll
        for (int d = 0; d < 2; ++d) acc[a][b][c][d] = (f32x4){0.f, 0.f, 0.f, 0.f};

  bf16x8 afA[4][2], afB[4][2], bq0[2][2], bq1[2][2];

  STGA(0, 0, 0); STGB(0, 0, 0); STGB(0, 1, 0); STGA(0, 1, 0);
  STGA(1, 0, 64);
  VMW(2);
  BAR();
  RD_A0(aA00, aA01, afA);
  RD_B0(aB00, aB01, bq0);

  int kb = 0;
#pragma unroll 1
  for (int j = 0; j < 15; ++j, kb += 128) {
    STGB(1, 0, kb + 64);
    RD_B1(aB00, aB01, bq1);
    LGKM(4); PRIO1(); MMAQ(afA, bq0, 0, 0); PRIO0(); VMW(4); BAR();
    STGB(1, 1, kb + 64);
    RD_A1(aA00, aA01, afB);
    LGKM(8); PRIO1(); MMAQ(afA, bq1, 0, 1); PRIO0(); VMW(4); BAR();
    STGA(1, 1, kb + 64);
    LGKM(0); PRIO1(); MMAQ(afB, bq0, 1, 0); PRIO0(); VMW(4); BAR();
    STGA(0, 0, kb + 128);
    RD_A0(aA10, aA11, afA);
    RD_B0(aB10, aB11, bq0);
    LGKM(12); PRIO1(); MMAQ(afB, bq1, 1, 1); PRIO0(); VMW(4); BAR();
    STGB(0, 0, kb + 128);
    RD_B1(aB10, aB11, bq1);
    LGKM(4); PRIO1(); MMAQ(afA, bq0, 0, 0); PRIO0(); VMW(4); BAR();
    STGB(0, 1, kb + 128);
    RD_A1(aA10, aA11, afB);
    LGKM(8); PRIO1(); MMAQ(afA, bq1, 0, 1); PRIO0(); VMW(4); BAR();
    STGA(0, 1, kb + 128);
    LGKM(0); PRIO1(); MMAQ(afB, bq0, 1, 0); PRIO0(); VMW(4); BAR();
    STGA(1, 0, kb + 192);
    RD_A0(aA00, aA01, afA);
    RD_B0(aB00, aB01, bq0);
    LGKM(12); PRIO1(); MMAQ(afB, bq1, 1, 1); PRIO0(); VMW(4); BAR();
  }
  {
    STGB(1, 0, kb + 64);
    RD_B1(aB00, aB01, bq1);
    LGKM(4); PRIO1(); MMAQ(afA, bq0, 0, 0); PRIO0(); VMW(4); BAR();
    STGB(1, 1, kb + 64);
    RD_A1(aA00, aA01, afB);
    LGKM(8); PRIO1(); MMAQ(afA, bq1, 0, 1); PRIO0(); VMW(4); BAR();
    STGA(1, 1, kb + 64);
    LGKM(0); PRIO1(); MMAQ(afB, bq0, 1, 0); PRIO0(); VMW(4); BAR();
    RD_A0(aA10, aA11, afA);
    RD_B0(aB10, aB11, bq0);
    LGKM(12); PRIO1(); MMAQ(afB, bq1, 1, 1); PRIO0(); VMW(2); BAR();
    RD_B1(aB10, aB11, bq1);
    LGKM(4); PRIO1(); MMAQ(afA, bq0, 0, 0); PRIO0(); VMW(0); BAR();
    RD_A1(aA10, aA11, afB);
    LGKM(8); PRIO1(); MMAQ(afA, bq1, 0, 1); PRIO0();
    LGKM(0); PRIO1(); MMAQ(afB, bq0, 1, 0); PRIO0();
    MMAQ(afB, bq1, 1, 1);
  }

  // ---------------- fused epilogue ----------------
  __syncthreads();
  float* red = (float*)&lds[0];

#pragma unroll
  for (int qm = 0; qm < 2; ++qm)
#pragma unroll
    for (int mi = 0; mi < 4; ++mi)
#pragma unroll
      for (int r = 0; r < 4; ++r) {
        float num = 0.f, den = 0.f;
#pragma unroll
        for (int qn = 0; qn < 2; ++qn)
#pragma unroll
          for (int ni = 0; ni < 2; ++ni) {
            float v = acc[qm][qn][mi][ni][r];
            float g = __shfl_xor(v, 1);
            float e = __expf(v * SINV);
            num += e * g;
            den += e;
          }
        num += __shfl_xor(num, 2); den += __shfl_xor(den, 2);
        num += __shfl_xor(num, 4); den += __shfl_xor(den, 4);
        num += __shfl_xor(num, 8); den += __shfl_xor(den, 8);
        if (l15 == 0) {
          int slot = qm * 16 + mi * 4 + r;
          red[((wid * 32 + slot) * 4 + s0) * 2 + 0] = num;
          red[((wid * 32 + slot) * 4 + s0) * 2 + 1] = den;
        }
      }
  __syncthreads();
  {
    int rloc = tid >> 1, which = tid & 1;
    int qm = rloc >> 7, wmr = (rloc >> 6) & 1, mi = (rloc >> 4) & 3;
    int lg = (rloc >> 2) & 3, r = rloc & 3;
    int slot = qm * 16 + mi * 4 + r;
    float v = 0.f;
#pragma unroll
    for (int w2 = 0; w2 < 4; ++w2)
      v += red[(((wmr * 4 + w2) * 32 + slot) * 4 + lg) * 2 + which];
    Pnd[((size_t)(brow + rloc) * 8 + bx) * 2 + which] = v;
  }
}

// ---------------- per-row finish ----------------
__global__ __launch_bounds__(256) void k_rowfinal(const float* __restrict__ Pnd,
                                                  float* __restrict__ part) {
  int row = blockIdx.x * 256 + threadIdx.x;
  const float4* p = (const float4*)(Pnd + (size_t)row * 16);
  float num = 0.f, den = 0.f;
#pragma unroll
  for (int i = 0; i < 4; ++i) {
    float4 v = p[i];
    num += v.x + v.z;
    den += v.y + v.w;
  }
  float logit = num / den;
  float ls = (logit >= 0.f) ? -log1pf(__expf(-logit))
                            : (logit - log1pf(__expf(logit)));
  __shared__ float red[4];
#pragma unroll
  for (int off = 32; off > 0; off >>= 1) ls += __shfl_down(ls, off);
  if ((threadIdx.x & 63) == 0) red[threadIdx.x >> 6] = ls;
  __syncthreads();
  if (threadIdx.x == 0) part[blockIdx.x] = red[0] + red[1] + red[2] + red[3];
}

__global__ __launch_bounds__(64) void k_final64(const float* __restrict__ part,
                                                float* __restrict__ out) {
  float v = part[threadIdx.x];
#pragma unroll
  for (int off = 32; off > 0; off >>= 1) v += __shfl_down(v, off);
  if (threadIdx.x == 0) out[0] = v;
}

extern "C" void kernel_launch(void* const* d_in, const int* in_sizes, int n_in,
                              void* d_out, int out_size, void* d_ws, size_t ws_size,
                              hipStream_t stream) {
  const float* D = (const float*)d_in[0];
  const float* S = (const float*)d_in[1];
  const float* W = (const float*)d_in[2];

  char* w = (char*)d_ws;
  u16* Dbf = (u16*)w; w += (size_t)NROWS * DS * 2;       // 67 MB
  u16* Bt = (u16*)w;  w += (size_t)DS * DS * 2;          // 8 MB (interleaved S/V)
  float* Pnd = (float*)w; w += (size_t)NROWS * 16 * 4;   // 1 MB
  float* part = (float*)w;                               // 256 B

  (void)hipFuncSetAttribute((const void*)k_gemm8,
                            hipFuncAttributeMaxDynamicSharedMemorySize, 131072);

  // one launch: V-GEMM (f32 in) + D convert + S->Bt, all independent
  k_pre<<<2432, 256, 0, stream>>>(D, S, W, Dbf, Bt);

  k_gemm8<<<512, 512, 131072, stream>>>(Dbf, Bt, Pnd);

  k_rowfinal<<<NROWS / 256, 256, 0, stream>>>(Pnd, part);
  k_final64<<<1, 64, 0, stream>>>(part, (float*)d_out);
}

// Round 10
// 167.807 us; speedup vs baseline: 2.0790x; 1.0117x over previous
//
#include <hip/hip_runtime.h>
#include <stdint.h>

typedef unsigned short u16;
typedef unsigned int u32;
typedef __attribute__((ext_vector_type(8))) short bf16x8;
typedef __attribute__((ext_vector_type(4))) float f32x4;
typedef __attribute__((ext_vector_type(4))) u32 u32x4;

#define DS 2048
#define NROWS 16384
#define MS 1024
#define K2 2048

__device__ __forceinline__ u16 f2bf(float f) {
  u32 u = __float_as_uint(f);
  u32 r = (u + 0x7fffu + ((u >> 16) & 1u)) >> 16;
  return (u16)r;
}

// ---------------- async global->LDS, 16B per lane ----------------
__device__ __forceinline__ void gload16(const u16* g, u16* l) {
  __builtin_amdgcn_global_load_lds(
      (const __attribute__((address_space(1))) void*)g,
      (__attribute__((address_space(3))) void*)l, 16, 0, 0);
}

#define DSR(d, a, IMM) \
  asm volatile("ds_read_b128 %0, %1 offset:%c2" : "=v"(d) : "v"(a), "n"(IMM))
#define CVTPK(d, lo, hi) \
  asm("v_cvt_pk_bf16_f32 %0, %1, %2" : "=v"(d) : "v"(lo), "v"(hi))
#define LGKM(N)                                              \
  asm volatile("s_waitcnt lgkmcnt(" #N ")" ::: "memory");    \
  __builtin_amdgcn_sched_barrier(0)
#define VMW(N) asm volatile("s_waitcnt vmcnt(" #N ")" ::: "memory")
#define SB0() __builtin_amdgcn_sched_barrier(0)
#define PRIO1() __builtin_amdgcn_s_setprio(1)
#define PRIO0() __builtin_amdgcn_s_setprio(0)
#define BAR() __builtin_amdgcn_s_barrier()

// cvt 2x f32x4 -> bf16x8 (element order k0..k7)
#define CVT8(dst, lo, hi)                                         \
  do {                                                            \
    u32 _c0, _c1, _c2, _c3;                                       \
    CVTPK(_c0, lo[0], lo[1]); CVTPK(_c1, lo[2], lo[3]);           \
    CVTPK(_c2, hi[0], hi[1]); CVTPK(_c3, hi[2], hi[3]);           \
    u32x4 _q = {_c0, _c1, _c2, _c3};                              \
    dst = *(bf16x8*)&_q;                                          \
  } while (0)

// ============ mega pre-kernel: V-GEMM(f32 in) + D convert + S->Bt ============
__global__ __launch_bounds__(256) void k_pre(const float* __restrict__ D,
                                             const float* __restrict__ S,
                                             const float* __restrict__ W,
                                             u16* __restrict__ Dbf,
                                             u16* __restrict__ Bt) {
  __shared__ float lsA[2][64 * 32];
  __shared__ float lsB[2][128 * 32];
  const int bid = blockIdx.x;
  const int tid = threadIdx.x;

  if (bid >= 256) {
    if (bid < 2304) {  // D convert
      size_t i = (size_t)(bid - 256) * 256 + tid;
#pragma unroll
      for (int it = 0; it < 16; ++it, i += (size_t)2048 * 256) {
        float4 v = ((const float4*)D)[i];
        ushort4 o;
        o.x = f2bf(v.x); o.y = f2bf(v.y); o.z = f2bf(v.z); o.w = f2bf(v.w);
        ((ushort4*)Dbf)[i] = o;
      }
    } else {  // S -> Bt even rows
      size_t j = (size_t)(bid - 2304) * 256 + tid;
#pragma unroll
      for (int it = 0; it < 16; ++it, j += (size_t)128 * 256) {
        float4 v = ((const float4*)S)[j];
        ushort4 o;
        o.x = f2bf(v.x); o.y = f2bf(v.y); o.z = f2bf(v.z); o.w = f2bf(v.w);
        int m = (int)(j >> 9), c4 = (int)(j & 511);
        ((ushort4*)Bt)[(size_t)m * 1024 + c4] = o;
      }
    }
    return;
  }

  // ---- V-GEMM: 64x128 tile, K=2048, f32 staged to LDS, cvt at fragment ----
  const int wid = tid >> 6, lane = tid & 63;
  const int brow = (bid >> 4) * 64;
  const int bcol = (bid & 15) * 128;
  const int wm = wid >> 1, wn = wid & 1;
  const int l15 = lane & 15, s0 = lane >> 4;

  const int sr = tid >> 3;
  const int soct = (tid & 7) ^ (sr & 7);
  const float* gS = S + (size_t)(brow + sr) * 2048 + soct * 4;
  const float* gW = W + (size_t)(bcol + sr) * 2048 + soct * 4;

  const u32 lbA = (u32)(uintptr_t)&lsA[0][0];
  const u32 lbB = (u32)(uintptr_t)&lsB[0][0];
  const u32 swz = (u32)(((2 * s0) ^ (l15 & 7)) * 16);
  const u32 aA = lbA + (u32)(wm * 32 + l15) * 128 + swz;
  const u32 aAx = aA ^ 16u;
  const u32 aB = lbB + (u32)(wn * 64 + l15) * 128 + swz;
  const u32 aBx = aB ^ 16u;

  f32x4 acc[2][4];
#pragma unroll
  for (int i = 0; i < 2; ++i)
#pragma unroll
    for (int j = 0; j < 4; ++j) acc[i][j] = (f32x4){0.f, 0.f, 0.f, 0.f};

#define VSTG(b, kt)                                                              \
  do {                                                                           \
    gload16((const u16*)(gS + (kt)),             (u16*)(&lsA[b][0] + wid * 256)); \
    gload16((const u16*)(gS + 32 * 2048 + (kt)), (u16*)(&lsA[b][1024] + wid * 256)); \
    gload16((const u16*)(gW + (kt)),             (u16*)(&lsB[b][0] + wid * 256)); \
    gload16((const u16*)(gW + 32 * 2048 + (kt)), (u16*)(&lsB[b][1024] + wid * 256)); \
    gload16((const u16*)(gW + 64 * 2048 + (kt)), (u16*)(&lsB[b][2048] + wid * 256)); \
    gload16((const u16*)(gW + 96 * 2048 + (kt)), (u16*)(&lsB[b][3072] + wid * 256)); \
  } while (0)

  VSTG(0, 0);
#pragma unroll 1
  for (int t = 0; t < 64; ++t) {
    const int b = t & 1;
    const u32 oA = (u32)(b * 8192), oB = (u32)(b * 16384);
    if (t < 63) {
      VSTG(b ^ 1, (t + 1) * 32);
      VMW(6);
    } else {
      VMW(0);
    }
    BAR(); SB0();
    f32x4 qa0, qa1, qa2, qa3;
    f32x4 qb0, qb1, qb2, qb3, qb4, qb5, qb6, qb7;
    DSR(qa0, aA + oA, 0);     DSR(qa1, aAx + oA, 0);
    DSR(qa2, aA + oA, 2048);  DSR(qa3, aAx + oA, 2048);
    DSR(qb0, aB + oB, 0);     DSR(qb1, aBx + oB, 0);
    DSR(qb2, aB + oB, 2048);  DSR(qb3, aBx + oB, 2048);
    DSR(qb4, aB + oB, 4096);  DSR(qb5, aBx + oB, 4096);
    DSR(qb6, aB + oB, 6144);  DSR(qb7, aBx + oB, 6144);
    LGKM(0);
    bf16x8 af[2], bfr[4];
    CVT8(af[0], qa0, qa1); CVT8(af[1], qa2, qa3);
    CVT8(bfr[0], qb0, qb1); CVT8(bfr[1], qb2, qb3);
    CVT8(bfr[2], qb4, qb5); CVT8(bfr[3], qb6, qb7);
    PRIO1();
#pragma unroll
    for (int mi = 0; mi < 2; ++mi)
#pragma unroll
      for (int ni = 0; ni < 4; ++ni)
        acc[mi][ni] = __builtin_amdgcn_mfma_f32_16x16x32_bf16(af[mi], bfr[ni],
                                                              acc[mi][ni], 0, 0, 0);
    PRIO0(); SB0();
    BAR();
  }
#undef VSTG

  const int crow0 = brow + wm * 32 + s0 * 4;
  const int ccol0 = bcol + wn * 64 + l15;
  u16* C = Bt + 2048;
#pragma unroll
  for (int mi = 0; mi < 2; ++mi)
#pragma unroll
    for (int ni = 0; ni < 4; ++ni)
#pragma unroll
      for (int r = 0; r < 4; ++r)
        C[(size_t)(crow0 + mi * 16 + r) * 4096 + (ccol0 + ni * 16)] =
            f2bf(acc[mi][ni][r]);
}

// ========== 256^2 GEMM, 4 barrier-groups/iter (r10) + fused softmax epilogue ===
// r10: r4 schedule with barriers halved — phases merged pairwise; all reads,
// stages, LGKM counts IDENTICAL (per-wave semantics position-invariant);
// VMW(2) at group ends (FIFO re-derived: every staged half-tile drains one
// group before its first read, behind a barrier).
#define SINV 0.022097086912079608f

#define RD_A0(k0, k1, dst)                              \
  DSR(dst[0][0], k0, 0);     DSR(dst[0][1], k1, 0);     \
  DSR(dst[1][0], k0, 2048);  DSR(dst[1][1], k1, 2048);  \
  DSR(dst[2][0], k0, 4096);  DSR(dst[2][1], k1, 4096);  \
  DSR(dst[3][0], k0, 6144);  DSR(dst[3][1], k1, 6144)
#define RD_A1(k0, k1, dst)                              \
  DSR(dst[0][0], k0, 16384); DSR(dst[0][1], k1, 16384); \
  DSR(dst[1][0], k0, 18432); DSR(dst[1][1], k1, 18432); \
  DSR(dst[2][0], k0, 20480); DSR(dst[2][1], k1, 20480); \
  DSR(dst[3][0], k0, 22528); DSR(dst[3][1], k1, 22528)
#define RD_B0(k0, k1, dst)                              \
  DSR(dst[0][0], k0, 0);     DSR(dst[0][1], k1, 0);     \
  DSR(dst[1][0], k0, 2048);  DSR(dst[1][1], k1, 2048)
#define RD_B1(k0, k1, dst)                              \
  DSR(dst[0][0], k0, 16384); DSR(dst[0][1], k1, 16384); \
  DSR(dst[1][0], k0, 18432); DSR(dst[1][1], k1, 18432)

#define MMAQ(AF, BQ, QM, QN)                                                       \
  do {                                                                             \
    _Pragma("unroll") for (int mi = 0; mi < 4; ++mi)                               \
        _Pragma("unroll") for (int ni = 0; ni < 2; ++ni) {                         \
      acc[QM][QN][mi][ni] = __builtin_amdgcn_mfma_f32_16x16x32_bf16(               \
          AF[mi][0], BQ[ni][0], acc[QM][QN][mi][ni], 0, 0, 0);                     \
      acc[QM][QN][mi][ni] = __builtin_amdgcn_mfma_f32_16x16x32_bf16(               \
          AF[mi][1], BQ[ni][1], acc[QM][QN][mi][ni], 0, 0, 0);                     \
    }                                                                              \
  } while (0)

#define STGA(b, h, kt)                                                            \
  do {                                                                            \
    gload16(pA + (size_t)((h) * 128) * K2 + (kt),                                 \
            &lds[(b) * 32768 + (h) * 8192 + wid * 512]);                          \
    gload16(pA + (size_t)((h) * 128 + 64) * K2 + (kt),                            \
            &lds[(b) * 32768 + (h) * 8192 + 4096 + wid * 512]);                   \
  } while (0)
#define STGB(b, h, kt)                                                            \
  do {                                                                            \
    gload16(pB + (size_t)((h) * 128) * K2 + (kt),                                 \
            &lds[(b) * 32768 + 16384 + (h) * 8192 + wid * 512]);                  \
    gload16(pB + (size_t)((h) * 128 + 64) * K2 + (kt),                            \
            &lds[(b) * 32768 + 16384 + (h) * 8192 + 4096 + wid * 512]);           \
  } while (0)

__global__ __launch_bounds__(512, 2) void k_gemm8(const u16* __restrict__ A,
                                                  const u16* __restrict__ Bt,
                                                  float* __restrict__ Pnd) {
  extern __shared__ u16 lds[];
  const int tid = threadIdx.x;
  const int wid = tid >> 6;
  const int lane = tid & 63;
  const int bid = blockIdx.x;
  const int swz = (bid & 7) * 64 + (bid >> 3);
  const int by = swz >> 3, bx = swz & 7;
  const int brow = by * 256, bcol = bx * 256;
  const int wm = wid >> 2, wn = wid & 3;
  const int l15 = lane & 15, s0 = lane >> 4;

  const int tr = tid >> 3;
  const int scol = ((tid & 7) ^ (tr & 7)) << 3;
  const u16* pA = A + (size_t)(brow + tr) * K2 + scol;
  const u16* pB = Bt + (size_t)(bcol + tr) * K2 + scol;

  const u32 lb = (u32)(uintptr_t)(&lds[0]);
  const u32 xorp = ((u32)(s0 ^ (lane & 7))) << 4;
  const u32 aA00 = lb + ((u32)(wm * 64 + l15) << 7) + xorp;
  const u32 aA01 = aA00 ^ 64u;
  const u32 aA10 = aA00 + 65536u;
  const u32 aA11 = aA10 ^ 64u;
  const u32 aB00 = lb + 32768u + ((u32)(wn * 32 + l15) << 7) + xorp;
  const u32 aB01 = aB00 ^ 64u;
  const u32 aB10 = aB00 + 65536u;
  const u32 aB11 = aB10 ^ 64u;

  f32x4 acc[2][2][4][2];
#pragma unroll
  for (int a = 0; a < 2; ++a)
#pragma unroll
    for (int b = 0; b < 2; ++b)
#pragma unroll
      for (int c = 0; c < 4; ++c)
#pragma unroll
        for (int d = 0; d < 2; ++d) acc[a][b][c][d] = (f32x4){0.f, 0.f, 0.f, 0.f};

  bf16x8 afA[4][2], afB[4][2], bq0[2][2], bq1[2][2];

  STGA(0, 0, 0); STGB(0, 0, 0); STGB(0, 1, 0); STGA(0, 1, 0);
  STGA(1, 0, 64);
  VMW(2);
  BAR();
  RD_A0(aA00, aA01, afA);
  RD_B0(aB00, aB01, bq0);

  int kb = 0;
#pragma unroll 1
  for (int j = 0; j < 15; ++j, kb += 128) {
    // G1 = P1+P2: consume buf0 quadrants (0,0),(0,1)
    STGB(1, 0, kb + 64);
    RD_B1(aB00, aB01, bq1);
    LGKM(4); PRIO1(); MMAQ(afA, bq0, 0, 0); PRIO0();
    STGB(1, 1, kb + 64);
    RD_A1(aA00, aA01, afB);
    LGKM(8); PRIO1(); MMAQ(afA, bq1, 0, 1); PRIO0(); VMW(2); BAR();
    // G2 = P3+P4: buf0 quadrants (1,0),(1,1); read buf1 h0 set
    STGA(1, 1, kb + 64);
    LGKM(0); PRIO1(); MMAQ(afB, bq0, 1, 0); PRIO0();
    STGA(0, 0, kb + 128);
    RD_A0(aA10, aA11, afA);
    RD_B0(aB10, aB11, bq0);
    LGKM(12); PRIO1(); MMAQ(afB, bq1, 1, 1); PRIO0(); VMW(2); BAR();
    // G3 = P5+P6: consume buf1 quadrants (0,0),(0,1)
    STGB(0, 0, kb + 128);
    RD_B1(aB10, aB11, bq1);
    LGKM(4); PRIO1(); MMAQ(afA, bq0, 0, 0); PRIO0();
    STGB(0, 1, kb + 128);
    RD_A1(aA10, aA11, afB);
    LGKM(8); PRIO1(); MMAQ(afA, bq1, 0, 1); PRIO0(); VMW(2); BAR();
    // G4 = P7+P8: buf1 quadrants (1,0),(1,1); read next buf0 h0 set
    STGA(0, 1, kb + 128);
    LGKM(0); PRIO1(); MMAQ(afB, bq0, 1, 0); PRIO0();
    STGA(1, 0, kb + 192);
    RD_A0(aA00, aA01, afA);
    RD_B0(aB00, aB01, bq0);
    LGKM(12); PRIO1(); MMAQ(afB, bq1, 1, 1); PRIO0(); VMW(2); BAR();
  }
  // ---- tail: tiles 30 (buf0) + 31 (buf1); kb == 1920 ----
  {
    // T-G1
    STGB(1, 0, kb + 64);
    RD_B1(aB00, aB01, bq1);
    LGKM(4); PRIO1(); MMAQ(afA, bq0, 0, 0); PRIO0();
    STGB(1, 1, kb + 64);
    RD_A1(aA00, aA01, afB);
    LGKM(8); PRIO1(); MMAQ(afA, bq1, 0, 1); PRIO0(); VMW(2); BAR();
    // T-G2
    STGA(1, 1, kb + 64);
    LGKM(0); PRIO1(); MMAQ(afB, bq0, 1, 0); PRIO0();
    RD_A0(aA10, aA11, afA);
    RD_B0(aB10, aB11, bq0);
    LGKM(12); PRIO1(); MMAQ(afB, bq1, 1, 1); PRIO0(); VMW(0); BAR();
    // T-G3: buf1, no staging
    RD_B1(aB10, aB11, bq1);
    LGKM(4); PRIO1(); MMAQ(afA, bq0, 0, 0); PRIO0();
    RD_A1(aA10, aA11, afB);
    LGKM(8); PRIO1(); MMAQ(afA, bq1, 0, 1); PRIO0();
    LGKM(0); PRIO1(); MMAQ(afB, bq0, 1, 0); MMAQ(afB, bq1, 1, 1); PRIO0();
  }

  // ---------------- fused epilogue ----------------
  __syncthreads();
  float* red = (float*)&lds[0];

#pragma unroll
  for (int qm = 0; qm < 2; ++qm)
#pragma unroll
    for (int mi = 0; mi < 4; ++mi)
#pragma unroll
      for (int r = 0; r < 4; ++r) {
        float num = 0.f, den = 0.f;
#pragma unroll
        for (int qn = 0; qn < 2; ++qn)
#pragma unroll
          for (int ni = 0; ni < 2; ++ni) {
            float v = acc[qm][qn][mi][ni][r];
            float g = __shfl_xor(v, 1);
            float e = __expf(v * SINV);
            num += e * g;
            den += e;
          }
        num += __shfl_xor(num, 2); den += __shfl_xor(den, 2);
        num += __shfl_xor(num, 4); den += __shfl_xor(den, 4);
        num += __shfl_xor(num, 8); den += __shfl_xor(den, 8);
        if (l15 == 0) {
          int slot = qm * 16 + mi * 4 + r;
          red[((wid * 32 + slot) * 4 + s0) * 2 + 0] = num;
          red[((wid * 32 + slot) * 4 + s0) * 2 + 1] = den;
        }
      }
  __syncthreads();
  {
    int rloc = tid >> 1, which = tid & 1;
    int qm = rloc >> 7, wmr = (rloc >> 6) & 1, mi = (rloc >> 4) & 3;
    int lg = (rloc >> 2) & 3, r = rloc & 3;
    int slot = qm * 16 + mi * 4 + r;
    float v = 0.f;
#pragma unroll
    for (int w2 = 0; w2 < 4; ++w2)
      v += red[(((wmr * 4 + w2) * 32 + slot) * 4 + lg) * 2 + which];
    Pnd[((size_t)(brow + rloc) * 8 + bx) * 2 + which] = v;
  }
}

// ---------------- per-row finish ----------------
__global__ __launch_bounds__(256) void k_rowfinal(const float* __restrict__ Pnd,
                                                  float* __restrict__ part) {
  int row = blockIdx.x * 256 + threadIdx.x;
  const float4* p = (const float4*)(Pnd + (size_t)row * 16);
  float num = 0.f, den = 0.f;
#pragma unroll
  for (int i = 0; i < 4; ++i) {
    float4 v = p[i];
    num += v.x + v.z;
    den += v.y + v.w;
  }
  float logit = num / den;
  float ls = (logit >= 0.f) ? -log1pf(__expf(-logit))
                            : (logit - log1pf(__expf(logit)));
  __shared__ float red[4];
#pragma unroll
  for (int off = 32; off > 0; off >>= 1) ls += __shfl_down(ls, off);
  if ((threadIdx.x & 63) == 0) red[threadIdx.x >> 6] = ls;
  __syncthreads();
  if (threadIdx.x == 0) part[blockIdx.x] = red[0] + red[1] + red[2] + red[3];
}

__global__ __launch_bounds__(64) void k_final64(const float* __restrict__ part,
                                                float* __restrict__ out) {
  float v = part[threadIdx.x];
#pragma unroll
  for (int off = 32; off > 0; off >>= 1) v += __shfl_down(v, off);
  if (threadIdx.x == 0) out[0] = v;
}

extern "C" void kernel_launch(void* const* d_in, const int* in_sizes, int n_in,
                              void* d_out, int out_size, void* d_ws, size_t ws_size,
                              hipStream_t stream) {
  const float* D = (const float*)d_in[0];
  const float* S = (const float*)d_in[1];
  const float* W = (const float*)d_in[2];

  char* w = (char*)d_ws;
  u16* Dbf = (u16*)w; w += (size_t)NROWS * DS * 2;       // 67 MB
  u16* Bt = (u16*)w;  w += (size_t)DS * DS * 2;          // 8 MB (interleaved S/V)
  float* Pnd = (float*)w; w += (size_t)NROWS * 16 * 4;   // 1 MB
  float* part = (float*)w;                               // 256 B

  (void)hipFuncSetAttribute((const void*)k_gemm8,
                            hipFuncAttributeMaxDynamicSharedMemorySize, 131072);

  k_pre<<<2432, 256, 0, stream>>>(D, S, W, Dbf, Bt);
  k_gemm8<<<512, 512, 131072, stream>>>(Dbf, Bt, Pnd);
  k_rowfinal<<<NROWS / 256, 256, 0, stream>>>(Pnd, part);
  k_final64<<<1, 64, 0, stream>>>(part, (float*)d_out);
}

// Round 11
// 167.155 us; speedup vs baseline: 2.0871x; 1.0039x over previous
//
#include <hip/hip_runtime.h>
#include <stdint.h>

typedef unsigned short u16;
typedef unsigned int u32;
typedef __attribute__((ext_vector_type(8))) short bf16x8;
typedef __attribute__((ext_vector_type(4))) float f32x4;
typedef __attribute__((ext_vector_type(4))) u32 u32x4;

#define DS 2048
#define NROWS 16384
#define MS 1024
#define K2 2048

__device__ __forceinline__ u16 f2bf(float f) {
  u32 u = __float_as_uint(f);
  u32 r = (u + 0x7fffu + ((u >> 16) & 1u)) >> 16;
  return (u16)r;
}

// ---------------- async global->LDS, 16B per lane ----------------
__device__ __forceinline__ void gload16(const u16* g, u16* l) {
  __builtin_amdgcn_global_load_lds(
      (const __attribute__((address_space(1))) void*)g,
      (__attribute__((address_space(3))) void*)l, 16, 0, 0);
}

#define DSR(d, a, IMM) \
  asm volatile("ds_read_b128 %0, %1 offset:%c2" : "=v"(d) : "v"(a), "n"(IMM))
#define CVTPK(d, lo, hi) \
  asm("v_cvt_pk_bf16_f32 %0, %1, %2" : "=v"(d) : "v"(lo), "v"(hi))
#define LGKM(N)                                              \
  asm volatile("s_waitcnt lgkmcnt(" #N ")" ::: "memory");    \
  __builtin_amdgcn_sched_barrier(0)
#define VMW(N) asm volatile("s_waitcnt vmcnt(" #N ")" ::: "memory")
#define SB0() __builtin_amdgcn_sched_barrier(0)
#define PRIO1() __builtin_amdgcn_s_setprio(1)
#define PRIO0() __builtin_amdgcn_s_setprio(0)
#define BAR() __builtin_amdgcn_s_barrier()

// cvt 2x f32x4 -> bf16x8 (element order k0..k7)
#define CVT8(dst, lo, hi)                                         \
  do {                                                            \
    u32 _c0, _c1, _c2, _c3;                                       \
    CVTPK(_c0, lo[0], lo[1]); CVTPK(_c1, lo[2], lo[3]);           \
    CVTPK(_c2, hi[0], hi[1]); CVTPK(_c3, hi[2], hi[3]);           \
    u32x4 _q = {_c0, _c1, _c2, _c3};                              \
    dst = *(bf16x8*)&_q;                                          \
  } while (0)

// ============ mega pre-kernel: V-GEMM(f32 in) + D convert + S->Bt ============
__global__ __launch_bounds__(256) void k_pre(const float* __restrict__ D,
                                             const float* __restrict__ S,
                                             const float* __restrict__ W,
                                             u16* __restrict__ Dbf,
                                             u16* __restrict__ Bt) {
  __shared__ float lsA[2][64 * 32];
  __shared__ float lsB[2][128 * 32];
  const int bid = blockIdx.x;
  const int tid = threadIdx.x;

  if (bid >= 256) {
    if (bid < 2304) {  // D convert
      size_t i = (size_t)(bid - 256) * 256 + tid;
#pragma unroll
      for (int it = 0; it < 16; ++it, i += (size_t)2048 * 256) {
        float4 v = ((const float4*)D)[i];
        ushort4 o;
        o.x = f2bf(v.x); o.y = f2bf(v.y); o.z = f2bf(v.z); o.w = f2bf(v.w);
        ((ushort4*)Dbf)[i] = o;
      }
    } else {  // S -> Bt even rows
      size_t j = (size_t)(bid - 2304) * 256 + tid;
#pragma unroll
      for (int it = 0; it < 16; ++it, j += (size_t)128 * 256) {
        float4 v = ((const float4*)S)[j];
        ushort4 o;
        o.x = f2bf(v.x); o.y = f2bf(v.y); o.z = f2bf(v.z); o.w = f2bf(v.w);
        int m = (int)(j >> 9), c4 = (int)(j & 511);
        ((ushort4*)Bt)[(size_t)m * 1024 + c4] = o;
      }
    }
    return;
  }

  // ---- V-GEMM: 64x128 tile, K=2048, f32 staged to LDS, cvt at fragment ----
  const int wid = tid >> 6, lane = tid & 63;
  const int brow = (bid >> 4) * 64;
  const int bcol = (bid & 15) * 128;
  const int wm = wid >> 1, wn = wid & 1;
  const int l15 = lane & 15, s0 = lane >> 4;

  const int sr = tid >> 3;
  const int soct = (tid & 7) ^ (sr & 7);
  const float* gS = S + (size_t)(brow + sr) * 2048 + soct * 4;
  const float* gW = W + (size_t)(bcol + sr) * 2048 + soct * 4;

  const u32 lbA = (u32)(uintptr_t)&lsA[0][0];
  const u32 lbB = (u32)(uintptr_t)&lsB[0][0];
  const u32 swz = (u32)(((2 * s0) ^ (l15 & 7)) * 16);
  const u32 aA = lbA + (u32)(wm * 32 + l15) * 128 + swz;
  const u32 aAx = aA ^ 16u;
  const u32 aB = lbB + (u32)(wn * 64 + l15) * 128 + swz;
  const u32 aBx = aB ^ 16u;

  f32x4 acc[2][4];
#pragma unroll
  for (int i = 0; i < 2; ++i)
#pragma unroll
    for (int j = 0; j < 4; ++j) acc[i][j] = (f32x4){0.f, 0.f, 0.f, 0.f};

#define VSTG(b, kt)                                                              \
  do {                                                                           \
    gload16((const u16*)(gS + (kt)),             (u16*)(&lsA[b][0] + wid * 256)); \
    gload16((const u16*)(gS + 32 * 2048 + (kt)), (u16*)(&lsA[b][1024] + wid * 256)); \
    gload16((const u16*)(gW + (kt)),             (u16*)(&lsB[b][0] + wid * 256)); \
    gload16((const u16*)(gW + 32 * 2048 + (kt)), (u16*)(&lsB[b][1024] + wid * 256)); \
    gload16((const u16*)(gW + 64 * 2048 + (kt)), (u16*)(&lsB[b][2048] + wid * 256)); \
    gload16((const u16*)(gW + 96 * 2048 + (kt)), (u16*)(&lsB[b][3072] + wid * 256)); \
  } while (0)

  VSTG(0, 0);
#pragma unroll 1
  for (int t = 0; t < 64; ++t) {
    const int b = t & 1;
    const u32 oA = (u32)(b * 8192), oB = (u32)(b * 16384);
    if (t < 63) {
      VSTG(b ^ 1, (t + 1) * 32);
      VMW(6);
    } else {
      VMW(0);
    }
    BAR(); SB0();
    f32x4 qa0, qa1, qa2, qa3;
    f32x4 qb0, qb1, qb2, qb3, qb4, qb5, qb6, qb7;
    DSR(qa0, aA + oA, 0);     DSR(qa1, aAx + oA, 0);
    DSR(qa2, aA + oA, 2048);  DSR(qa3, aAx + oA, 2048);
    DSR(qb0, aB + oB, 0);     DSR(qb1, aBx + oB, 0);
    DSR(qb2, aB + oB, 2048);  DSR(qb3, aBx + oB, 2048);
    DSR(qb4, aB + oB, 4096);  DSR(qb5, aBx + oB, 4096);
    DSR(qb6, aB + oB, 6144);  DSR(qb7, aBx + oB, 6144);
    LGKM(0);
    bf16x8 af[2], bfr[4];
    CVT8(af[0], qa0, qa1); CVT8(af[1], qa2, qa3);
    CVT8(bfr[0], qb0, qb1); CVT8(bfr[1], qb2, qb3);
    CVT8(bfr[2], qb4, qb5); CVT8(bfr[3], qb6, qb7);
    PRIO1();
#pragma unroll
    for (int mi = 0; mi < 2; ++mi)
#pragma unroll
      for (int ni = 0; ni < 4; ++ni)
        acc[mi][ni] = __builtin_amdgcn_mfma_f32_16x16x32_bf16(af[mi], bfr[ni],
                                                              acc[mi][ni], 0, 0, 0);
    PRIO0(); SB0();
    BAR();
  }
#undef VSTG

  const int crow0 = brow + wm * 32 + s0 * 4;
  const int ccol0 = bcol + wn * 64 + l15;
  u16* C = Bt + 2048;
#pragma unroll
  for (int mi = 0; mi < 2; ++mi)
#pragma unroll
    for (int ni = 0; ni < 4; ++ni)
#pragma unroll
      for (int r = 0; r < 4; ++r)
        C[(size_t)(crow0 + mi * 16 + r) * 4096 + (ccol0 + ni * 16)] =
            f2bf(acc[mi][ni][r]);
}

// ===== 256^2 GEMM, 4 groups/iter, r11 stage-lead rebalance + fused epilogue ===
// r11: same reads/LGKM/MFMA as r10; 3 stages moved one group earlier so every
// staged half-tile has >=1 full group (~2100cy >> HBM ~900cy) before its
// drain-deadline. Group-end waits: VMW(4),VMW(4),VMW(4),VMW(2). WAR audited:
// each moved write lands >=1 barrier after all waves' reads of old data drain.
#define SINV 0.022097086912079608f

#define RD_A0(k0, k1, dst)                              \
  DSR(dst[0][0], k0, 0);     DSR(dst[0][1], k1, 0);     \
  DSR(dst[1][0], k0, 2048);  DSR(dst[1][1], k1, 2048);  \
  DSR(dst[2][0], k0, 4096);  DSR(dst[2][1], k1, 4096);  \
  DSR(dst[3][0], k0, 6144);  DSR(dst[3][1], k1, 6144)
#define RD_A1(k0, k1, dst)                              \
  DSR(dst[0][0], k0, 16384); DSR(dst[0][1], k1, 16384); \
  DSR(dst[1][0], k0, 18432); DSR(dst[1][1], k1, 18432); \
  DSR(dst[2][0], k0, 20480); DSR(dst[2][1], k1, 20480); \
  DSR(dst[3][0], k0, 22528); DSR(dst[3][1], k1, 22528)
#define RD_B0(k0, k1, dst)                              \
  DSR(dst[0][0], k0, 0);     DSR(dst[0][1], k1, 0);     \
  DSR(dst[1][0], k0, 2048);  DSR(dst[1][1], k1, 2048)
#define RD_B1(k0, k1, dst)                              \
  DSR(dst[0][0], k0, 16384); DSR(dst[0][1], k1, 16384); \
  DSR(dst[1][0], k0, 18432); DSR(dst[1][1], k1, 18432)

#define MMAQ(AF, BQ, QM, QN)                                                       \
  do {                                                                             \
    _Pragma("unroll") for (int mi = 0; mi < 4; ++mi)                               \
        _Pragma("unroll") for (int ni = 0; ni < 2; ++ni) {                         \
      acc[QM][QN][mi][ni] = __builtin_amdgcn_mfma_f32_16x16x32_bf16(               \
          AF[mi][0], BQ[ni][0], acc[QM][QN][mi][ni], 0, 0, 0);                     \
      acc[QM][QN][mi][ni] = __builtin_amdgcn_mfma_f32_16x16x32_bf16(               \
          AF[mi][1], BQ[ni][1], acc[QM][QN][mi][ni], 0, 0, 0);                     \
    }                                                                              \
  } while (0)

#define STGA(b, h, kt)                                                            \
  do {                                                                            \
    gload16(pA + (size_t)((h) * 128) * K2 + (kt),                                 \
            &lds[(b) * 32768 + (h) * 8192 + wid * 512]);                          \
    gload16(pA + (size_t)((h) * 128 + 64) * K2 + (kt),                            \
            &lds[(b) * 32768 + (h) * 8192 + 4096 + wid * 512]);                   \
  } while (0)
#define STGB(b, h, kt)                                                            \
  do {                                                                            \
    gload16(pB + (size_t)((h) * 128) * K2 + (kt),                                 \
            &lds[(b) * 32768 + 16384 + (h) * 8192 + wid * 512]);                  \
    gload16(pB + (size_t)((h) * 128 + 64) * K2 + (kt),                            \
            &lds[(b) * 32768 + 16384 + (h) * 8192 + 4096 + wid * 512]);           \
  } while (0)

__global__ __launch_bounds__(512, 2) void k_gemm8(const u16* __restrict__ A,
                                                  const u16* __restrict__ Bt,
                                                  float* __restrict__ Pnd) {
  extern __shared__ u16 lds[];
  const int tid = threadIdx.x;
  const int wid = tid >> 6;
  const int lane = tid & 63;
  const int bid = blockIdx.x;
  const int swz = (bid & 7) * 64 + (bid >> 3);
  const int by = swz >> 3, bx = swz & 7;
  const int brow = by * 256, bcol = bx * 256;
  const int wm = wid >> 2, wn = wid & 3;
  const int l15 = lane & 15, s0 = lane >> 4;

  const int tr = tid >> 3;
  const int scol = ((tid & 7) ^ (tr & 7)) << 3;
  const u16* pA = A + (size_t)(brow + tr) * K2 + scol;
  const u16* pB = Bt + (size_t)(bcol + tr) * K2 + scol;

  const u32 lb = (u32)(uintptr_t)(&lds[0]);
  const u32 xorp = ((u32)(s0 ^ (lane & 7))) << 4;
  const u32 aA00 = lb + ((u32)(wm * 64 + l15) << 7) + xorp;
  const u32 aA01 = aA00 ^ 64u;
  const u32 aA10 = aA00 + 65536u;
  const u32 aA11 = aA10 ^ 64u;
  const u32 aB00 = lb + 32768u + ((u32)(wn * 32 + l15) << 7) + xorp;
  const u32 aB01 = aB00 ^ 64u;
  const u32 aB10 = aB00 + 65536u;
  const u32 aB11 = aB10 ^ 64u;

  f32x4 acc[2][2][4][2];
#pragma unroll
  for (int a = 0; a < 2; ++a)
#pragma unroll
    for (int b = 0; b < 2; ++b)
#pragma unroll
      for (int c = 0; c < 4; ++c)
#pragma unroll
        for (int d = 0; d < 2; ++d) acc[a][b][c][d] = (f32x4){0.f, 0.f, 0.f, 0.f};

  bf16x8 afA[4][2], afB[4][2], bq0[2][2], bq1[2][2];

  STGA(0, 0, 0); STGB(0, 0, 0); STGB(0, 1, 0); STGA(0, 1, 0);
  STGA(1, 0, 64);
  VMW(2);
  BAR();
  RD_A0(aA00, aA01, afA);
  RD_B0(aB00, aB01, bq0);

  int kb = 0;
#pragma unroll 1
  for (int j = 0; j < 15; ++j, kb += 128) {
    // G1: consume buf0 top; stage buf1.Bh0, buf1.Bh1, buf1.Ah1
    STGB(1, 0, kb + 64);
    RD_B1(aB00, aB01, bq1);
    LGKM(4); PRIO1(); MMAQ(afA, bq0, 0, 0); PRIO0();
    STGB(1, 1, kb + 64);
    STGA(1, 1, kb + 64);
    RD_A1(aA00, aA01, afB);
    LGKM(8); PRIO1(); MMAQ(afA, bq1, 0, 1); PRIO0(); VMW(4); BAR();
    // G2: consume buf0 bottom; stage buf0'.Ah0, buf0'.Bh0; read buf1 h0 set
    LGKM(0); PRIO1(); MMAQ(afB, bq0, 1, 0); PRIO0();
    STGA(0, 0, kb + 128);
    STGB(0, 0, kb + 128);
    RD_A0(aA10, aA11, afA);
    RD_B0(aB10, aB11, bq0);
    LGKM(12); PRIO1(); MMAQ(afB, bq1, 1, 1); PRIO0(); VMW(4); BAR();
    // G3: consume buf1 top; stage buf0'.Bh1, buf0'.Ah1
    STGB(0, 1, kb + 128);
    RD_B1(aB10, aB11, bq1);
    LGKM(4); PRIO1(); MMAQ(afA, bq0, 0, 0); PRIO0();
    STGA(0, 1, kb + 128);
    RD_A1(aA10, aA11, afB);
    LGKM(8); PRIO1(); MMAQ(afA, bq1, 0, 1); PRIO0(); VMW(4); BAR();
    // G4: consume buf1 bottom; stage buf1'.Ah0; read next buf0 h0 set
    LGKM(0); PRIO1(); MMAQ(afB, bq0, 1, 0); PRIO0();
    STGA(1, 0, kb + 192);
    RD_A0(aA00, aA01, afA);
    RD_B0(aB00, aB01, bq0);
    LGKM(12); PRIO1(); MMAQ(afB, bq1, 1, 1); PRIO0(); VMW(2); BAR();
  }
  // ---- tail: tiles 30 (buf0) + 31 (buf1); kb == 1920 ----
  {
    // T-G1
    STGB(1, 0, kb + 64);
    RD_B1(aB00, aB01, bq1);
    LGKM(4); PRIO1(); MMAQ(afA, bq0, 0, 0); PRIO0();
    STGB(1, 1, kb + 64);
    STGA(1, 1, kb + 64);
    RD_A1(aA00, aA01, afB);
    LGKM(8); PRIO1(); MMAQ(afA, bq1, 0, 1); PRIO0(); VMW(4); BAR();
    // T-G2 (no next-tile staging)
    LGKM(0); PRIO1(); MMAQ(afB, bq0, 1, 0); PRIO0();
    RD_A0(aA10, aA11, afA);
    RD_B0(aB10, aB11, bq0);
    LGKM(12); PRIO1(); MMAQ(afB, bq1, 1, 1); PRIO0(); VMW(0); BAR();
    // T-G3: consume buf1, no barriers needed after
    RD_B1(aB10, aB11, bq1);
    LGKM(4); PRIO1(); MMAQ(afA, bq0, 0, 0); PRIO0();
    RD_A1(aA10, aA11, afB);
    LGKM(8); PRIO1(); MMAQ(afA, bq1, 0, 1); PRIO0();
    LGKM(0); PRIO1(); MMAQ(afB, bq0, 1, 0); MMAQ(afB, bq1, 1, 1); PRIO0();
  }

  // ---------------- fused epilogue ----------------
  __syncthreads();
  float* red = (float*)&lds[0];

#pragma unroll
  for (int qm = 0; qm < 2; ++qm)
#pragma unroll
    for (int mi = 0; mi < 4; ++mi)
#pragma unroll
      for (int r = 0; r < 4; ++r) {
        float num = 0.f, den = 0.f;
#pragma unroll
        for (int qn = 0; qn < 2; ++qn)
#pragma unroll
          for (int ni = 0; ni < 2; ++ni) {
            float v = acc[qm][qn][mi][ni][r];
            float g = __shfl_xor(v, 1);
            float e = __expf(v * SINV);
            num += e * g;
            den += e;
          }
        num += __shfl_xor(num, 2); den += __shfl_xor(den, 2);
        num += __shfl_xor(num, 4); den += __shfl_xor(den, 4);
        num += __shfl_xor(num, 8); den += __shfl_xor(den, 8);
        if (l15 == 0) {
          int slot = qm * 16 + mi * 4 + r;
          red[((wid * 32 + slot) * 4 + s0) * 2 + 0] = num;
          red[((wid * 32 + slot) * 4 + s0) * 2 + 1] = den;
        }
      }
  __syncthreads();
  {
    int rloc = tid >> 1, which = tid & 1;
    int qm = rloc >> 7, wmr = (rloc >> 6) & 1, mi = (rloc >> 4) & 3;
    int lg = (rloc >> 2) & 3, r = rloc & 3;
    int slot = qm * 16 + mi * 4 + r;
    float v = 0.f;
#pragma unroll
    for (int w2 = 0; w2 < 4; ++w2)
      v += red[(((wmr * 4 + w2) * 32 + slot) * 4 + lg) * 2 + which];
    Pnd[((size_t)(brow + rloc) * 8 + bx) * 2 + which] = v;
  }
}

// ---------------- per-row finish ----------------
__global__ __launch_bounds__(256) void k_rowfinal(const float* __restrict__ Pnd,
                                                  float* __restrict__ part) {
  int row = blockIdx.x * 256 + threadIdx.x;
  const float4* p = (const float4*)(Pnd + (size_t)row * 16);
  float num = 0.f, den = 0.f;
#pragma unroll
  for (int i = 0; i < 4; ++i) {
    float4 v = p[i];
    num += v.x + v.z;
    den += v.y + v.w;
  }
  float logit = num / den;
  float ls = (logit >= 0.f) ? -log1pf(__expf(-logit))
                            : (logit - log1pf(__expf(logit)));
  __shared__ float red[4];
#pragma unroll
  for (int off = 32; off > 0; off >>= 1) ls += __shfl_down(ls, off);
  if ((threadIdx.x & 63) == 0) red[threadIdx.x >> 6] = ls;
  __syncthreads();
  if (threadIdx.x == 0) part[blockIdx.x] = red[0] + red[1] + red[2] + red[3];
}

__global__ __launch_bounds__(64) void k_final64(const float* __restrict__ part,
                                                float* __restrict__ out) {
  float v = part[threadIdx.x];
#pragma unroll
  for (int off = 32; off > 0; off >>= 1) v += __shfl_down(v, off);
  if (threadIdx.x == 0) out[0] = v;
}

extern "C" void kernel_launch(void* const* d_in, const int* in_sizes, int n_in,
                              void* d_out, int out_size, void* d_ws, size_t ws_size,
                              hipStream_t stream) {
  const float* D = (const float*)d_in[0];
  const float* S = (const float*)d_in[1];
  const float* W = (const float*)d_in[2];

  char* w = (char*)d_ws;
  u16* Dbf = (u16*)w; w += (size_t)NROWS * DS * 2;       // 67 MB
  u16* Bt = (u16*)w;  w += (size_t)DS * DS * 2;          // 8 MB (interleaved S/V)
  float* Pnd = (float*)w; w += (size_t)NROWS * 16 * 4;   // 1 MB
  float* part = (float*)w;                               // 256 B

  (void)hipFuncSetAttribute((const void*)k_gemm8,
                            hipFuncAttributeMaxDynamicSharedMemorySize, 131072);

  k_pre<<<2432, 256, 0, stream>>>(D, S, W, Dbf, Bt);
  k_gemm8<<<512, 512, 131072, stream>>>(Dbf, Bt, Pnd);
  k_rowfinal<<<NROWS / 256, 256, 0, stream>>>(Pnd, part);
  k_final64<<<1, 64, 0, stream>>>(part, (float*)d_out);
}